// Round 3
// baseline (284.771 us; speedup 1.0000x reference)
//
#include <hip/hip_runtime.h>
#include <hip/hip_bf16.h>

// CentralSpecificModel: per-species 2-layer MLP (256 -> 1024 -> 256), 4 species,
// N=65536 rows, fp32 in/out. Bucket rows by species; fused per-64-row-tile
// kernel does GEMM1+silu+GEMM2 with bf16 MFMA (16x16x32). Weights pre-swizzled
// to B-fragment order, loaded straight from global (L2-resident).
// R3: hid-chunk 256 (4 chunks) halves Xs LDS re-reads (the busiest pipe);
// single-buffer Hs (same 8 barriers, 69.6KB LDS, 2 blk/CU); per-ks streamed
// B-frag loads under full unroll (compiler pipelines); coalesced prep.

#define N_ATOMS 65536
#define D_IN 256
#define D_HID 1024
#define D_OUT 256
#define TPS 1024   // max 64-row tiles per species (worst case: all rows one species)

typedef __attribute__((ext_vector_type(8))) short short8;
typedef __attribute__((ext_vector_type(4))) float float4e;

// ws layout (bytes):
//   [0, 256)           cnt[4] padded: cnt[s] at int offset s*16 (64B apart)
//   [256, 1048832)     bucket[4][65536] int
//   [1048832, 3145984) W1 swizzled bf16 fragments (4*256*1024)
//   [3145984, 5243136) W2 swizzled bf16 fragments (4*1024*256)
#define WS_BUCKET_OFF 256
#define WS_W1_OFF 1048832
#define WS_W2_OFF 3145984

__device__ __forceinline__ short f2bf(float f) {
  unsigned u = __builtin_bit_cast(unsigned, f);
  unsigned r = (u + 0x7FFFu + ((u >> 16) & 1u)) >> 16;   // round-to-nearest-even
  return (short)r;
}

// Swizzle W1/W2 fp32 -> bf16 MFMA B-fragment order; zero padded counters.
// B-frag (16x16x32): lane L=g*16+lr holds B[k0 + 8g + j][n0 + lr], j=0..7,
// frag memory: lane-major, each lane's 8 elems contiguous (16B).
// One thread per (k-row, 16-col stripe): reads 64B contiguous (fully
// coalesced), writes 16 bf16 scattered at stride 16B (dense within 256B,
// merges in L2 write combining).
__global__ void prep_kernel(const float* __restrict__ W1, const float* __restrict__ W2,
                            short* __restrict__ w1sw, short* __restrict__ w2sw,
                            int* __restrict__ cnt) {
  int gid = blockIdx.x * 256 + threadIdx.x;   // 131072 threads
  if (gid < 64) cnt[gid] = 0;
  float vals[16];
  short* dst;
  if (gid < 65536) {            // W1: (s, k 0..255, nt 0..63)
    int nt = gid & 63;
    int k  = (gid >> 6) & 255;
    int s  = gid >> 14;
    const float4* src = (const float4*)(W1 + ((size_t)(s * 256 + k)) * 1024 + nt * 16);
    float4 v0 = src[0], v1 = src[1], v2 = src[2], v3 = src[3];
    vals[0]=v0.x; vals[1]=v0.y; vals[2]=v0.z; vals[3]=v0.w;
    vals[4]=v1.x; vals[5]=v1.y; vals[6]=v1.z; vals[7]=v1.w;
    vals[8]=v2.x; vals[9]=v2.y; vals[10]=v2.z; vals[11]=v2.w;
    vals[12]=v3.x; vals[13]=v3.y; vals[14]=v3.z; vals[15]=v3.w;
    int ks = k >> 5, kk = k & 31, g = kk >> 3, j = kk & 7;
    dst = w1sw + ((size_t)((s * 64 + nt) * 8 + ks)) * 512 + g * 128 + j;
  } else {                      // W2: (s, k 0..1023, nt 0..15)
    int g2 = gid - 65536;
    int nt = g2 & 15;
    int k  = (g2 >> 4) & 1023;
    int s  = g2 >> 14;
    const float4* src = (const float4*)(W2 + ((size_t)(s * 1024 + k)) * 256 + nt * 16);
    float4 v0 = src[0], v1 = src[1], v2 = src[2], v3 = src[3];
    vals[0]=v0.x; vals[1]=v0.y; vals[2]=v0.z; vals[3]=v0.w;
    vals[4]=v1.x; vals[5]=v1.y; vals[6]=v1.z; vals[7]=v1.w;
    vals[8]=v2.x; vals[9]=v2.y; vals[10]=v2.z; vals[11]=v2.w;
    vals[12]=v3.x; vals[13]=v3.y; vals[14]=v3.z; vals[15]=v3.w;
    int kt = k >> 5, kk = k & 31, g = kk >> 3, j = kk & 7;
    dst = w2sw + ((size_t)((s * 16 + nt) * 32 + kt)) * 512 + g * 128 + j;
  }
  #pragma unroll
  for (int lr = 0; lr < 16; ++lr) dst[lr * 8] = f2bf(vals[lr]);
}

// Bucket rows by species. Block-level histogram -> 4 atomics per block, to
// 64B-padded counters.
__global__ void count_fill_kernel(const int* __restrict__ species,
                                  int* __restrict__ cnt, int* __restrict__ bucket) {
  int tid = threadIdx.x;
  int i = blockIdx.x * 256 + tid;
  int s = species[i] & 3;
  int lane = tid & 63, wid = tid >> 6;
  __shared__ int wcnt[4][4];    // [wave][species]
  __shared__ int wbase[4][4];
  unsigned long long m0 = __ballot(s == 0);
  unsigned long long m1 = __ballot(s == 1);
  unsigned long long m2 = __ballot(s == 2);
  unsigned long long m3 = __ballot(s == 3);
  if (lane == 0) {
    wcnt[wid][0] = __popcll(m0); wcnt[wid][1] = __popcll(m1);
    wcnt[wid][2] = __popcll(m2); wcnt[wid][3] = __popcll(m3);
  }
  __syncthreads();
  if (tid < 4) {
    int ss = tid;
    int c0 = wcnt[0][ss], c1 = wcnt[1][ss], c2 = wcnt[2][ss], c3 = wcnt[3][ss];
    int base = atomicAdd(&cnt[ss * 16], c0 + c1 + c2 + c3);
    wbase[0][ss] = base;
    wbase[1][ss] = base + c0;
    wbase[2][ss] = base + c0 + c1;
    wbase[3][ss] = base + c0 + c1 + c2;
  }
  __syncthreads();
  unsigned long long below = (1ull << lane) - 1ull;
  int rank = 0;
  if (s == 0) rank = __popcll(m0 & below);
  if (s == 1) rank = __popcll(m1 & below);
  if (s == 2) rank = __popcll(m2 & below);
  if (s == 3) rank = __popcll(m3 & below);
  bucket[s * N_ATOMS + wbase[wid][s] + rank] = i;
}

// Fused per-tile MLP. Block = 256 threads (4 waves), tile = 64 rows.
// LDS: Xs 64x280 bf16 (35840B) + Hs 64x264 bf16 (33792B) = 69632B -> 2 blk/CU.
// 4 hid-chunks of 256 cols. Per chunk: GEMM1 (wave: 64 rows x 64 cols, K=256)
// -> barrier (prev GEMM2 readers done) -> silu -> Hs -> barrier -> GEMM2
// (wave: 64 rows x 64 out cols, K=256 chunk k-slice). 8 barriers total.
// Both LDS strides verified conflict-free for the b128 frag-read pattern
// (bank-quad = (a*lr+g) mod 8, uniform 8 lanes/quad = the 64-lane minimum).
#define XS_STRIDE 280
#define HS_STRIDE 264
__global__ __launch_bounds__(256, 2) void fused_kernel(
    const float* __restrict__ x, const int* __restrict__ cntArr,
    const int* __restrict__ bucket, const short* __restrict__ w1sw,
    const short* __restrict__ w2sw, const float* __restrict__ b1,
    const float* __restrict__ b2, float* __restrict__ out) {
  int s = blockIdx.x >> 10;         // TPS = 1024
  int t = blockIdx.x & (TPS - 1);
  int cnt = cntArr[s * 16];
  int r0 = t * 64;
  if (r0 >= cnt) return;
  int nrows = min(64, cnt - r0);
  const int* buck = bucket + s * N_ATOMS + r0;

  __shared__ short Xs[64 * XS_STRIDE];
  __shared__ short Hs[64 * HS_STRIDE];

  int tid = threadIdx.x;

  // Stage gathered x tile -> bf16 LDS.
  for (int i = 0; i < 8; ++i) {
    int id = tid + i * 256;
    int r = id >> 5;          // row 0..63
    int g = id & 31;          // 8-float group
    short8 v = {};
    if (r < nrows) {
      const float4* src = (const float4*)(x + (size_t)buck[r] * D_IN + g * 8);
      float4 f0 = src[0];
      float4 f1 = src[1];
      v[0] = f2bf(f0.x); v[1] = f2bf(f0.y); v[2] = f2bf(f0.z); v[3] = f2bf(f0.w);
      v[4] = f2bf(f1.x); v[5] = f2bf(f1.y); v[6] = f2bf(f1.z); v[7] = f2bf(f1.w);
    }
    *(short8*)(Xs + r * XS_STRIDE + g * 8) = v;
  }

  int lane = tid & 63;
  int wid = tid >> 6;
  int lr = lane & 15;          // A row / B,C col within 16-tile
  int lk = (lane >> 4) * 8;    // k base within 32-kstep
  int lq = (lane >> 4) * 4;    // C/D row base

  // Preload biases.
  float bias1[4][4];
  #pragma unroll
  for (int c = 0; c < 4; ++c)
    #pragma unroll
    for (int ct = 0; ct < 4; ++ct)
      bias1[c][ct] = b1[s * D_HID + c * 256 + wid * 64 + ct * 16 + lr];
  float bias2[4];
  #pragma unroll
  for (int ct = 0; ct < 4; ++ct)
    bias2[ct] = b2[s * D_OUT + wid * 64 + ct * 16 + lr];

  __syncthreads();   // Xs ready

  float4e accY[4][4] = {};     // 64 rows x 64 out cols per wave

  #pragma unroll
  for (int c = 0; c < 4; ++c) {
    // ---- GEMM1: H chunk [64 x 256] = Xs @ W1[:, c*256..) ; wave: 64 cols ----
    float4e acc1[4][4] = {};
    #pragma unroll
    for (int ks = 0; ks < 8; ++ks) {
      short8 b[4];
      #pragma unroll
      for (int ct = 0; ct < 4; ++ct) {
        int nt = c * 16 + wid * 4 + ct;
        b[ct] = *(const short8*)(w1sw + ((size_t)((s * 64 + nt) * 8 + ks)) * 512 + lane * 8);
      }
      short8 a[4];
      #pragma unroll
      for (int rt = 0; rt < 4; ++rt)
        a[rt] = *(const short8*)(Xs + (rt * 16 + lr) * XS_STRIDE + ks * 32 + lk);
      #pragma unroll
      for (int rt = 0; rt < 4; ++rt)
        #pragma unroll
        for (int ct = 0; ct < 4; ++ct)
          acc1[rt][ct] = __builtin_amdgcn_mfma_f32_16x16x32_bf16(a[rt], b[ct], acc1[rt][ct], 0, 0, 0);
    }
    __syncthreads();   // prev chunk's GEMM2 done reading Hs
    // ---- bias + silu -> Hs ----
    #pragma unroll
    for (int ct = 0; ct < 4; ++ct) {
      int nloc = wid * 64 + ct * 16 + lr;
      float bias = bias1[c][ct];
      #pragma unroll
      for (int rt = 0; rt < 4; ++rt) {
        float4e v4 = acc1[rt][ct];
        #pragma unroll
        for (int q = 0; q < 4; ++q) {
          float pre = v4[q] + bias;
          float val = pre / (1.0f + __expf(-pre));     // silu
          Hs[(rt * 16 + lq + q) * HS_STRIDE + nloc] = f2bf(val);
        }
      }
    }
    __syncthreads();   // Hs chunk visible
    // ---- GEMM2 partial: accY += H_chunk @ W2[c*256.., :] ; wave: 64 out ----
    #pragma unroll
    for (int ks = 0; ks < 8; ++ks) {
      short8 b[4];
      #pragma unroll
      for (int ct = 0; ct < 4; ++ct) {
        int nt = wid * 4 + ct;
        int kt = c * 8 + ks;
        b[ct] = *(const short8*)(w2sw + ((size_t)((s * 16 + nt) * 32 + kt)) * 512 + lane * 8);
      }
      short8 a[4];
      #pragma unroll
      for (int rt = 0; rt < 4; ++rt)
        a[rt] = *(const short8*)(Hs + (rt * 16 + lr) * HS_STRIDE + ks * 32 + lk);
      #pragma unroll
      for (int rt = 0; rt < 4; ++rt)
        #pragma unroll
        for (int ct = 0; ct < 4; ++ct)
          accY[rt][ct] = __builtin_amdgcn_mfma_f32_16x16x32_bf16(a[rt], b[ct], accY[rt][ct], 0, 0, 0);
    }
  }

  // ---- epilogue: scatter y + b2 to original rows ----
  #pragma unroll
  for (int ct = 0; ct < 4; ++ct) {
    int n = wid * 64 + ct * 16 + lr;
    float bias = bias2[ct];
    #pragma unroll
    for (int rt = 0; rt < 4; ++rt) {
      #pragma unroll
      for (int q = 0; q < 4; ++q) {
        int r = rt * 16 + lq + q;
        if (r < nrows)
          out[(size_t)buck[r] * D_OUT + n] = accY[rt][ct][q] + bias;
      }
    }
  }
}

extern "C" void kernel_launch(void* const* d_in, const int* in_sizes, int n_in,
                              void* d_out, int out_size, void* d_ws, size_t ws_size,
                              hipStream_t stream) {
  const float* x  = (const float*)d_in[0];
  const int* spc  = (const int*)d_in[1];
  const float* W1 = (const float*)d_in[2];
  const float* b1 = (const float*)d_in[3];
  const float* W2 = (const float*)d_in[4];
  const float* b2 = (const float*)d_in[5];
  float* out = (float*)d_out;

  int*   cnt    = (int*)d_ws;
  int*   bucket = (int*)((char*)d_ws + WS_BUCKET_OFF);
  short* w1sw   = (short*)((char*)d_ws + WS_W1_OFF);
  short* w2sw   = (short*)((char*)d_ws + WS_W2_OFF);

  prep_kernel<<<512, 256, 0, stream>>>(W1, W2, w1sw, w2sw, cnt);
  count_fill_kernel<<<N_ATOMS / 256, 256, 0, stream>>>(spc, cnt, bucket);
  fused_kernel<<<4 * TPS, 256, 0, stream>>>(x, cnt, bucket, w1sw, w2sw, b1, b2, out);
}

// Round 5
// 275.363 us; speedup vs baseline: 1.0342x; 1.0342x over previous
//
#include <hip/hip_runtime.h>
#include <hip/hip_bf16.h>

// CentralSpecificModel: per-species 2-layer MLP (256 -> 1024 -> 256), 4 species,
// N=65536 rows, fp32 in/out. Bucket rows by species; fused per-64-row-tile
// kernel does GEMM1+silu+GEMM2 with bf16 MFMA (16x16x32). Weights pre-swizzled
// to B-fragment order, loaded straight from global (L2-resident).
// R5 = R4 with the compile fix: bit-extract __hip_bfloat162 via union
// (__builtin_bit_cast rejects it: non-trivially-copyable).
// R4 notes: prep rewritten as LDS-transpose (R3's prep had 16x scattered 2B
// stores per thread: ~85us for 12MB of work). Fused: hw-packed bf16 cvt +
// rcp-based silu to trim VALU (27% busy). Tiling untouched: 128 VGPR + 128
// AGPR is exactly the 2-waves/SIMD cap.

#define N_ATOMS 65536
#define D_IN 256
#define D_HID 1024
#define D_OUT 256
#define TPS 1024   // max 64-row tiles per species (worst case: all rows one species)

typedef __attribute__((ext_vector_type(8))) short short8;
typedef __attribute__((ext_vector_type(4))) float float4e;

// ws layout (bytes):
//   [0, 256)           cnt[4] padded: cnt[s] at int offset s*16 (64B apart)
//   [256, 1048832)     bucket[4][65536] int
//   [1048832, 3145984) W1 swizzled bf16 fragments (4*256*1024)
//   [3145984, 5243136) W2 swizzled bf16 fragments (4*1024*256)
#define WS_BUCKET_OFF 256
#define WS_W1_OFF 1048832
#define WS_W2_OFF 3145984

__device__ __forceinline__ short f2bf(float f) {
  unsigned u = __builtin_bit_cast(unsigned, f);
  unsigned r = (u + 0x7FFFu + ((u >> 16) & 1u)) >> 16;   // round-to-nearest-even
  return (short)r;
}

// Packed f32x2 -> bf16x2 (v_cvt_pk_bf16_f32 on gfx950), RNE.
__device__ __forceinline__ unsigned pk2bf(float a, float b) {
  float2 f2; f2.x = a; f2.y = b;
  union { __hip_bfloat162 h; unsigned u; } cvt;
  cvt.h = __float22bfloat162_rn(f2);
  return cvt.u;
}

union S8U {
  short8 s8;
  unsigned u[4];
};

// Swizzle W1/W2 fp32 -> bf16 MFMA B-fragment order via LDS transpose.
// B-frag (16x16x32): lane L=g*16+lr holds B[k0 + 8g + j][n0 + lr], j=0..7,
// frag memory lane-major, each lane's 8 elems contiguous (16B).
// Per block: one (32 k-rows x 64 n-cols) tile. Global reads 256B-coalesced,
// LDS tile stride 66 shorts (33 dwords, odd -> conflict-free for both the
// 4x b32 write pattern and the strided u16 frag reads), frag writes 1KB
// contiguous per wave.
__global__ __launch_bounds__(256) void prep_kernel(
    const float* __restrict__ W1, const float* __restrict__ W2,
    short* __restrict__ w1sw, short* __restrict__ w2sw,
    int* __restrict__ cnt) {
  __shared__ short tile[32 * 66];
  int bid = blockIdx.x;           // 1024 blocks: 512 for W1, 512 for W2
  int tid = threadIdx.x;
  if (bid == 0 && tid < 64) cnt[tid] = 0;

  const float* src;
  short* dstBase;
  int fragStride;                 // frag-index stride between consecutive nt
  if (bid < 512) {                // W1: [4][256][1024]
    int ntq = bid & 15;           // 16 groups of 4 n-tiles (64 cols)
    int ks  = (bid >> 4) & 7;     // k-step of 32
    int s   = bid >> 7;
    int kk = tid >> 3;            // 0..31
    int cg = tid & 7;             // 8-float column group
    src = W1 + ((size_t)(s * 256 + ks * 32 + kk)) * 1024 + ntq * 64 + cg * 8;
    dstBase = w1sw + ((size_t)((s * 64 + ntq * 4) * 8 + ks)) * 512;
    fragStride = 8 * 512;
  } else {                        // W2: [4][1024][256]
    int b = bid - 512;
    int ntq = b & 3;              // 4 groups of 4 n-tiles
    int kt  = (b >> 2) & 31;      // k-step of 32
    int s   = b >> 7;
    int kk = tid >> 3;
    int cg = tid & 7;
    src = W2 + ((size_t)(s * 1024 + kt * 32 + kk)) * 256 + ntq * 64 + cg * 8;
    dstBase = w2sw + ((size_t)((s * 16 + ntq * 4) * 32 + kt)) * 512;
    fragStride = 32 * 512;
  }

  {   // load 8 floats (2x float4, 256B-coalesced per 8 threads) -> bf16 tile
    int kk = tid >> 3, cg = tid & 7;
    const float4* s4 = (const float4*)src;
    float4 f0 = s4[0], f1 = s4[1];
    unsigned p0 = pk2bf(f0.x, f0.y), p1 = pk2bf(f0.z, f0.w);
    unsigned p2 = pk2bf(f1.x, f1.y), p3 = pk2bf(f1.z, f1.w);
    unsigned* t32 = (unsigned*)(tile + kk * 66 + cg * 8);
    t32[0] = p0; t32[1] = p1; t32[2] = p2; t32[3] = p3;
  }
  __syncthreads();
  {   // emit fragments: thread t -> n-tile f = t>>6, lane l = t&63
    int f = tid >> 6, l = tid & 63;
    int g = l >> 4, lr = l & 15;
    S8U v;
    #pragma unroll
    for (int j = 0; j < 8; j += 2) {
      short a = tile[(g * 8 + j) * 66 + f * 16 + lr];
      short b = tile[(g * 8 + j + 1) * 66 + f * 16 + lr];
      v.u[j >> 1] = (unsigned short)a | ((unsigned)(unsigned short)b << 16);
    }
    *(short8*)(dstBase + (size_t)f * fragStride + l * 8) = v.s8;
  }
}

// Bucket rows by species. Block-level histogram -> 4 atomics per block, to
// 64B-padded counters.
__global__ void count_fill_kernel(const int* __restrict__ species,
                                  int* __restrict__ cnt, int* __restrict__ bucket) {
  int tid = threadIdx.x;
  int i = blockIdx.x * 256 + tid;
  int s = species[i] & 3;
  int lane = tid & 63, wid = tid >> 6;
  __shared__ int wcnt[4][4];    // [wave][species]
  __shared__ int wbase[4][4];
  unsigned long long m0 = __ballot(s == 0);
  unsigned long long m1 = __ballot(s == 1);
  unsigned long long m2 = __ballot(s == 2);
  unsigned long long m3 = __ballot(s == 3);
  if (lane == 0) {
    wcnt[wid][0] = __popcll(m0); wcnt[wid][1] = __popcll(m1);
    wcnt[wid][2] = __popcll(m2); wcnt[wid][3] = __popcll(m3);
  }
  __syncthreads();
  if (tid < 4) {
    int ss = tid;
    int c0 = wcnt[0][ss], c1 = wcnt[1][ss], c2 = wcnt[2][ss], c3 = wcnt[3][ss];
    int base = atomicAdd(&cnt[ss * 16], c0 + c1 + c2 + c3);
    wbase[0][ss] = base;
    wbase[1][ss] = base + c0;
    wbase[2][ss] = base + c0 + c1;
    wbase[3][ss] = base + c0 + c1 + c2;
  }
  __syncthreads();
  unsigned long long below = (1ull << lane) - 1ull;
  int rank = 0;
  if (s == 0) rank = __popcll(m0 & below);
  if (s == 1) rank = __popcll(m1 & below);
  if (s == 2) rank = __popcll(m2 & below);
  if (s == 3) rank = __popcll(m3 & below);
  bucket[s * N_ATOMS + wbase[wid][s] + rank] = i;
}

// Fused per-tile MLP. Block = 256 threads (4 waves), tile = 64 rows.
// LDS: Xs 64x280 bf16 (35840B) + Hs 64x264 bf16 (33792B) = 69632B -> 2 blk/CU.
// 4 hid-chunks of 256 cols. Per chunk: GEMM1 (wave: 64 rows x 64 cols, K=256)
// -> barrier -> silu -> Hs -> barrier -> GEMM2 (wave: 64 rows x 64 out cols).
#define XS_STRIDE 280
#define HS_STRIDE 264
__global__ __launch_bounds__(256, 2) void fused_kernel(
    const float* __restrict__ x, const int* __restrict__ cntArr,
    const int* __restrict__ bucket, const short* __restrict__ w1sw,
    const short* __restrict__ w2sw, const float* __restrict__ b1,
    const float* __restrict__ b2, float* __restrict__ out) {
  int s = blockIdx.x >> 10;         // TPS = 1024
  int t = blockIdx.x & (TPS - 1);
  int cnt = cntArr[s * 16];
  int r0 = t * 64;
  if (r0 >= cnt) return;
  int nrows = min(64, cnt - r0);
  const int* buck = bucket + s * N_ATOMS + r0;

  __shared__ short Xs[64 * XS_STRIDE];
  __shared__ short Hs[64 * HS_STRIDE];

  int tid = threadIdx.x;

  // Stage gathered x tile -> bf16 LDS.
  for (int i = 0; i < 8; ++i) {
    int id = tid + i * 256;
    int r = id >> 5;          // row 0..63
    int g = id & 31;          // 8-float group
    S8U v; v.s8 = short8{};
    if (r < nrows) {
      const float4* src = (const float4*)(x + (size_t)buck[r] * D_IN + g * 8);
      float4 f0 = src[0];
      float4 f1 = src[1];
      v.u[0] = pk2bf(f0.x, f0.y); v.u[1] = pk2bf(f0.z, f0.w);
      v.u[2] = pk2bf(f1.x, f1.y); v.u[3] = pk2bf(f1.z, f1.w);
    }
    *(short8*)(Xs + r * XS_STRIDE + g * 8) = v.s8;
  }

  int lane = tid & 63;
  int wid = tid >> 6;
  int lr = lane & 15;          // A row / B,C col within 16-tile
  int lk = (lane >> 4) * 8;    // k base within 32-kstep
  int lq = (lane >> 4) * 4;    // C/D row base

  // Preload biases.
  float bias1[4][4];
  #pragma unroll
  for (int c = 0; c < 4; ++c)
    #pragma unroll
    for (int ct = 0; ct < 4; ++ct)
      bias1[c][ct] = b1[s * D_HID + c * 256 + wid * 64 + ct * 16 + lr];
  float bias2[4];
  #pragma unroll
  for (int ct = 0; ct < 4; ++ct)
    bias2[ct] = b2[s * D_OUT + wid * 64 + ct * 16 + lr];

  __syncthreads();   // Xs ready

  float4e accY[4][4] = {};     // 64 rows x 64 out cols per wave

  #pragma unroll
  for (int c = 0; c < 4; ++c) {
    // ---- GEMM1: H chunk [64 x 256] = Xs @ W1[:, c*256..) ; wave: 64 cols ----
    float4e acc1[4][4] = {};
    #pragma unroll
    for (int ks = 0; ks < 8; ++ks) {
      short8 b[4];
      #pragma unroll
      for (int ct = 0; ct < 4; ++ct) {
        int nt = c * 16 + wid * 4 + ct;
        b[ct] = *(const short8*)(w1sw + ((size_t)((s * 64 + nt) * 8 + ks)) * 512 + lane * 8);
      }
      short8 a[4];
      #pragma unroll
      for (int rt = 0; rt < 4; ++rt)
        a[rt] = *(const short8*)(Xs + (rt * 16 + lr) * XS_STRIDE + ks * 32 + lk);
      #pragma unroll
      for (int rt = 0; rt < 4; ++rt)
        #pragma unroll
        for (int ct = 0; ct < 4; ++ct)
          acc1[rt][ct] = __builtin_amdgcn_mfma_f32_16x16x32_bf16(a[rt], b[ct], acc1[rt][ct], 0, 0, 0);
    }
    __syncthreads();   // prev chunk's GEMM2 done reading Hs
    // ---- bias + silu -> Hs (packed bf16 cvt, rcp-based silu) ----
    #pragma unroll
    for (int ct = 0; ct < 4; ++ct) {
      int nloc = wid * 64 + ct * 16 + lr;
      float bias = bias1[c][ct];
      #pragma unroll
      for (int rt = 0; rt < 4; ++rt) {
        float4e v4 = acc1[rt][ct];
        float sv[4];
        #pragma unroll
        for (int q = 0; q < 4; ++q) {
          float pre = v4[q] + bias;
          sv[q] = pre * __builtin_amdgcn_rcpf(1.0f + __expf(-pre));   // silu
        }
        unsigned p01 = pk2bf(sv[0], sv[1]);
        unsigned p23 = pk2bf(sv[2], sv[3]);
        int rbase = (rt * 16 + lq) * HS_STRIDE + nloc;
        Hs[rbase]                 = (short)(p01 & 0xffff);
        Hs[rbase + HS_STRIDE]     = (short)(p01 >> 16);
        Hs[rbase + 2 * HS_STRIDE] = (short)(p23 & 0xffff);
        Hs[rbase + 3 * HS_STRIDE] = (short)(p23 >> 16);
      }
    }
    __syncthreads();   // Hs chunk visible
    // ---- GEMM2 partial: accY += H_chunk @ W2[c*256.., :] ; wave: 64 out ----
    #pragma unroll
    for (int ks = 0; ks < 8; ++ks) {
      short8 b[4];
      #pragma unroll
      for (int ct = 0; ct < 4; ++ct) {
        int nt = wid * 4 + ct;
        int kt = c * 8 + ks;
        b[ct] = *(const short8*)(w2sw + ((size_t)((s * 16 + nt) * 32 + kt)) * 512 + lane * 8);
      }
      short8 a[4];
      #pragma unroll
      for (int rt = 0; rt < 4; ++rt)
        a[rt] = *(const short8*)(Hs + (rt * 16 + lr) * HS_STRIDE + ks * 32 + lk);
      #pragma unroll
      for (int rt = 0; rt < 4; ++rt)
        #pragma unroll
        for (int ct = 0; ct < 4; ++ct)
          accY[rt][ct] = __builtin_amdgcn_mfma_f32_16x16x32_bf16(a[rt], b[ct], accY[rt][ct], 0, 0, 0);
    }
  }

  // ---- epilogue: scatter y + b2 to original rows ----
  #pragma unroll
  for (int ct = 0; ct < 4; ++ct) {
    int n = wid * 64 + ct * 16 + lr;
    float bias = bias2[ct];
    #pragma unroll
    for (int rt = 0; rt < 4; ++rt) {
      #pragma unroll
      for (int q = 0; q < 4; ++q) {
        int r = rt * 16 + lq + q;
        if (r < nrows)
          out[(size_t)buck[r] * D_OUT + n] = accY[rt][ct][q] + bias;
      }
    }
  }
}

extern "C" void kernel_launch(void* const* d_in, const int* in_sizes, int n_in,
                              void* d_out, int out_size, void* d_ws, size_t ws_size,
                              hipStream_t stream) {
  const float* x  = (const float*)d_in[0];
  const int* spc  = (const int*)d_in[1];
  const float* W1 = (const float*)d_in[2];
  const float* b1 = (const float*)d_in[3];
  const float* W2 = (const float*)d_in[4];
  const float* b2 = (const float*)d_in[5];
  float* out = (float*)d_out;

  int*   cnt    = (int*)d_ws;
  int*   bucket = (int*)((char*)d_ws + WS_BUCKET_OFF);
  short* w1sw   = (short*)((char*)d_ws + WS_W1_OFF);
  short* w2sw   = (short*)((char*)d_ws + WS_W2_OFF);

  prep_kernel<<<1024, 256, 0, stream>>>(W1, W2, w1sw, w2sw, cnt);
  count_fill_kernel<<<N_ATOMS / 256, 256, 0, stream>>>(spc, cnt, bucket);
  fused_kernel<<<4 * TPS, 256, 0, stream>>>(x, cnt, bucket, w1sw, w2sw, b1, b2, out);
}